// Round 9
// baseline (104.084 us; speedup 1.0000x reference)
//
#include <hip/hip_runtime.h>

// Problem constants: B=4, N=512, M=512, D=128, H=256, DOUT=128
#define BB    4
#define NN    512
#define MM    512
#define DD    128
#define HH    256
#define DOUTC 128

// ============================================================================
// ROUND 9 = ATTRIBUTION EXPERIMENT. Kernels are byte-identical to round 8.
// precompute_ac is launched 4x (pure function -> idempotent, graph-safe).
//   P = (dur9 - dur8) / 3  isolates precompute's true cost.
// Predicted: P ~= 13-15 us if the W1 L1-BW model is right (dur ~= 91-97);
// if dur9 ~= 55-60, precompute is cheap and fused_main is the ~48 us pig.
// ============================================================================

typedef float v2f __attribute__((ext_vector_type(2)));
typedef float v4f __attribute__((ext_vector_type(4)));

__device__ __forceinline__ v4f shfl_xor4(v4f v, int m) {
    v4f r;
    r.x = __shfl_xor(v.x, m, 64);
    r.y = __shfl_xor(v.y, m, 64);
    r.z = __shfl_xor(v.z, m, 64);
    r.w = __shfl_xor(v.w, m, 64);
    return r;
}

// ---------------------------------------------------------------------------
// Kernel 1: precompute (256 blocks x 1024 threads, 16 rows/block) — as round 8
// ---------------------------------------------------------------------------
__global__ __launch_bounds__(1024) void precompute_ac(
    const float* __restrict__ X, const float* __restrict__ Y,
    const float* __restrict__ W1, const float* __restrict__ b1,
    float* __restrict__ AC)
{
    __shared__ __align__(16) float rows16[16][DD];   // 8 KB
    const int bid = blockIdx.x;
    const int t   = threadIdx.x;
    const int isC = bid >> 7;
    const int r0  = (bid & 127) * 16;                // global row (b*512+m)
    const float* src = isC ? X : Y;

    if (t < 512)
        reinterpret_cast<v4f*>(&rows16[0][0])[t] =
            reinterpret_cast<const v4f*>(src + (size_t)r0 * DD)[t];
    __syncthreads();

    const int hq = t & 63, h0 = hq * 4;
    const int r  = t >> 6;                           // wave-uniform row
    const float* wp = W1 + (isC ? DD * HH : 0) + h0;

    v4f acc = (v4f){0.f, 0.f, 0.f, 0.f};
#pragma unroll
    for (int chunk = 0; chunk < 4; ++chunk) {
        const int dbase = chunk * 32;
#pragma unroll 2
        for (int dg = dbase; dg < dbase + 32; dg += 4) {
            const v4f rv = *reinterpret_cast<const v4f*>(&rows16[r][dg]); // bcast
            const v4f w0 = *reinterpret_cast<const v4f*>(&wp[(dg + 0) * HH]);
            const v4f w1 = *reinterpret_cast<const v4f*>(&wp[(dg + 1) * HH]);
            const v4f w2 = *reinterpret_cast<const v4f*>(&wp[(dg + 2) * HH]);
            const v4f w3 = *reinterpret_cast<const v4f*>(&wp[(dg + 3) * HH]);
            acc += w0 * rv.x;
            acc += w1 * rv.y;
            acc += w2 * rv.z;
            acc += w3 * rv.w;
        }
        if (chunk < 3) __syncthreads();   // keep waves in lockstep for L1 reuse
    }

    if (isC) acc += *reinterpret_cast<const v4f*>(&b1[h0]);
    *reinterpret_cast<v4f*>(&AC[((size_t)(isC * 2048 + r0 + r)) * HH + h0]) = acc;
}

// ---------------------------------------------------------------------------
// Kernel 2: fused abs-sum + W2 epilogue — as round 8
// ---------------------------------------------------------------------------
__global__ __launch_bounds__(1024) void fused_main(
    const float* __restrict__ A, const float* __restrict__ C,
    const float* __restrict__ W2, const float* __restrict__ b2,
    float* __restrict__ out)
{
    __shared__ __align__(16) v4f scratch[1536];     // 24 KB: qm-partials / red
    __shared__ __align__(16) v4f satp[3][4][16];    // 3 KB
    __shared__ __align__(16) float S[8][HH];        // 8 KB
    const int bid = blockIdx.x;
    const int b   = bid >> 6;
    const int n0  = (bid & 63) * 8;
    const int t   = threadIdx.x;

    // ---- phase A ----
    const int w    = t >> 6;
    const int l    = t & 63;
    const int hg   = w & 3;
    const int qm   = w >> 2;
    const int hq   = l & 15;
    const int msub = l >> 4;
    const int h0   = hg * 64 + hq * 4;

    const float* Cb = C + ((size_t)(b * NN + n0)) * HH + h0;
    v4f c[8];
#pragma unroll
    for (int j = 0; j < 8; ++j)
        c[j] = *reinterpret_cast<const v4f*>(&Cb[(size_t)j * HH]);

    v4f acc[8], sat = (v4f){0.f, 0.f, 0.f, 0.f};
#pragma unroll
    for (int j = 0; j < 8; ++j) acc[j] = (v4f){0.f, 0.f, 0.f, 0.f};

    // m = qm*128 + i*4 + msub, i = 0..31
    const float* Ab = A + ((size_t)(b * MM + qm * 128 + msub)) * HH + h0;
#pragma unroll 4
    for (int i = 0; i < 32; ++i) {
        const v4f a = *reinterpret_cast<const v4f*>(&Ab[(size_t)i * 4 * HH]);
        sat += a;
#pragma unroll
        for (int j = 0; j < 8; ++j) {
            const v4f s = a + c[j];
            acc[j].x += fabsf(s.x);
            acc[j].y += fabsf(s.y);
            acc[j].z += fabsf(s.z);
            acc[j].w += fabsf(s.w);
        }
    }

    // ---- reduce msub (in-register butterfly over lane bits 4,5) ----
#pragma unroll
    for (int mask = 16; mask <= 32; mask <<= 1) {
#pragma unroll
        for (int j = 0; j < 8; ++j) acc[j] += shfl_xor4(acc[j], mask);
        sat += shfl_xor4(sat, mask);
    }

    // ---- reduce qm via LDS (plain writes, no atomics) ----
    if (qm > 0 && l < 16) {
#pragma unroll
        for (int j = 0; j < 8; ++j)
            scratch[(((qm - 1) * 4 + hg) * 8 + j) * 16 + l] = acc[j];
        satp[qm - 1][hg][l] = sat;
    }
    __syncthreads();

    if (qm == 0 && l < 16) {
#pragma unroll
        for (int p = 0; p < 3; ++p) {
#pragma unroll
            for (int j = 0; j < 8; ++j)
                acc[j] += scratch[((p * 4 + hg) * 8 + j) * 16 + l];
            sat += satp[p][hg][l];
        }
#pragma unroll
        for (int j = 0; j < 8; ++j) {
            const v4f sv = 0.5f * (sat + 512.f * c[j] + acc[j]);
            *reinterpret_cast<v4f*>(&S[j][h0]) = sv;
        }
    }
    __syncthreads();

    // ---- phase C: out = S*W2 + 512*b2, k split 4 ways ----
    const int o0 = (t & 31) * 4;
    const int r  = (t >> 5) & 7;
    const int kq = t >> 8;
    const int k0 = kq * 64;
    v4f a4 = (v4f){0.f, 0.f, 0.f, 0.f};
    const float* w2p = W2 + o0;
#pragma unroll 4
    for (int k = k0; k < k0 + 64; k += 4) {
        const v4f sv = *reinterpret_cast<const v4f*>(&S[r][k]);       // broadcast
        const v4f wA = *reinterpret_cast<const v4f*>(&w2p[(k + 0) * DOUTC]);
        const v4f wB = *reinterpret_cast<const v4f*>(&w2p[(k + 1) * DOUTC]);
        const v4f wC = *reinterpret_cast<const v4f*>(&w2p[(k + 2) * DOUTC]);
        const v4f wD = *reinterpret_cast<const v4f*>(&w2p[(k + 3) * DOUTC]);
        a4 += wA * sv.x;
        a4 += wB * sv.y;
        a4 += wC * sv.z;
        a4 += wD * sv.w;
    }
    if (kq) scratch[(kq - 1) * 256 + (t & 255)] = a4;   // reuse 12 KB of scratch
    __syncthreads();
    if (kq == 0) {
#pragma unroll
        for (int p = 0; p < 3; ++p) a4 += scratch[p * 256 + t];
        a4 += 512.f * (*reinterpret_cast<const v4f*>(&b2[o0]));
        *reinterpret_cast<v4f*>(&out[((size_t)(b * NN + n0 + r)) * DOUTC + o0]) = a4;
    }
}

// ---------------------------------------------------------------------------
extern "C" void kernel_launch(void* const* d_in, const int* in_sizes, int n_in,
                              void* d_out, int out_size, void* d_ws, size_t ws_size,
                              hipStream_t stream) {
    const float* X  = (const float*)d_in[0];
    const float* Y  = (const float*)d_in[1];
    const float* W1 = (const float*)d_in[2];
    const float* b1 = (const float*)d_in[3];
    const float* W2 = (const float*)d_in[4];
    const float* b2 = (const float*)d_in[5];
    float* out = (float*)d_out;

    float* AC = (float*)d_ws;        // 4 MB: A rows 0..2047, C rows 2048..4095
    float* A  = AC;
    float* Cm = AC + 2048 * HH;

    // ATTRIBUTION: launch precompute 4x (idempotent). P = (dur9 - dur8)/3.
    hipLaunchKernelGGL(precompute_ac, dim3(256), dim3(1024), 0, stream,
                       X, Y, W1, b1, AC);
    hipLaunchKernelGGL(precompute_ac, dim3(256), dim3(1024), 0, stream,
                       X, Y, W1, b1, AC);
    hipLaunchKernelGGL(precompute_ac, dim3(256), dim3(1024), 0, stream,
                       X, Y, W1, b1, AC);
    hipLaunchKernelGGL(precompute_ac, dim3(256), dim3(1024), 0, stream,
                       X, Y, W1, b1, AC);
    hipLaunchKernelGGL(fused_main, dim3(256), dim3(1024), 0, stream,
                       A, Cm, W2, b2, out);
}

// Round 10
// 43.037 us; speedup vs baseline: 2.4185x; 2.4185x over previous
//
#include <hip/hip_runtime.h>

// Problem constants: B=4, N=512, M=512, D=128, H=256, DOUT=128
#define BB    4
#define NN    512
#define MM    512
#define DD    128
#define HH    256
#define DOUTC 128

typedef float v4f __attribute__((ext_vector_type(4)));

__device__ __forceinline__ v4f shfl_xor4(v4f v, int m) {
    v4f r;
    r.x = __shfl_xor(v.x, m, 64);
    r.y = __shfl_xor(v.y, m, 64);
    r.z = __shfl_xor(v.z, m, 64);
    r.w = __shfl_xor(v.w, m, 64);
    return r;
}

// ---------------------------------------------------------------------------
// Kernel 1: precompute (256 blocks x 1024 threads, 16 rows/block)
// Round-9 attribution: this kernel was 16.7 us == W1-redundancy model
// (16 row-slots x 128KB = 512 MB L2 reads). Fix: R=4 register tiling.
// Thread = (hq=t&63 -> 4 h, dq=(t>>6)&3 -> 32 d, rs=t>>8 -> 4 rows).
// Each thread reuses every W1 load across 4 rows -> W1 traffic 128 MB.
// dq-partials merged via ONE plain-write LDS stage (48 KB), no atomics.
// ---------------------------------------------------------------------------
__global__ __launch_bounds__(1024) void precompute_ac(
    const float* __restrict__ X, const float* __restrict__ Y,
    const float* __restrict__ W1, const float* __restrict__ b1,
    float* __restrict__ AC)
{
    __shared__ __align__(16) float rows[16][DD];     // 8 KB
    __shared__ __align__(16) v4f mrg[3][4][4][64];   // 48 KB: [dq-1][rs][r][hq]
    const int bid = blockIdx.x;
    const int t   = threadIdx.x;
    const int isC = bid >> 7;
    const int r0  = (bid & 127) * 16;                // global row (b*512+m)
    const float* src = isC ? X : Y;

    if (t < 512)
        reinterpret_cast<v4f*>(&rows[0][0])[t] =
            reinterpret_cast<const v4f*>(src + (size_t)r0 * DD)[t];
    __syncthreads();

    const int hq = t & 63;            // h-quad: h = hq*4 .. +3
    const int dq = (t >> 6) & 3;      // d-chunk: d = dq*32 .. +31 (wave-uniform)
    const int rs = t >> 8;            // row-group: rows rs*4 .. +3 (wave-uniform)
    const int d0 = dq * 32;
    const float* wp = W1 + (isC ? DD * HH : 0) + hq * 4;

    v4f acc[4];
#pragma unroll
    for (int r = 0; r < 4; ++r) acc[r] = (v4f){0.f, 0.f, 0.f, 0.f};

#pragma unroll 2
    for (int dg = 0; dg < 32; dg += 4) {
        const int d = d0 + dg;
        const v4f w0 = *reinterpret_cast<const v4f*>(&wp[(d + 0) * HH]);
        const v4f w1 = *reinterpret_cast<const v4f*>(&wp[(d + 1) * HH]);
        const v4f w2 = *reinterpret_cast<const v4f*>(&wp[(d + 2) * HH]);
        const v4f w3 = *reinterpret_cast<const v4f*>(&wp[(d + 3) * HH]);
#pragma unroll
        for (int r = 0; r < 4; ++r) {
            const v4f rv = *reinterpret_cast<const v4f*>(&rows[rs * 4 + r][d]); // bcast
            acc[r] += w0 * rv.x;
            acc[r] += w1 * rv.y;
            acc[r] += w2 * rv.z;
            acc[r] += w3 * rv.w;
        }
    }

    // merge 4 dq-partials: dq>0 write once, dq==0 sums (plain LDS, no atomics)
    if (dq > 0) {
#pragma unroll
        for (int r = 0; r < 4; ++r) mrg[dq - 1][rs][r][hq] = acc[r];
    }
    __syncthreads();
    if (dq == 0) {
#pragma unroll
        for (int r = 0; r < 4; ++r) {
#pragma unroll
            for (int p = 0; p < 3; ++p) acc[r] += mrg[p][rs][r][hq];
        }
        v4f bias = (v4f){0.f, 0.f, 0.f, 0.f};
        if (isC) bias = *reinterpret_cast<const v4f*>(&b1[hq * 4]);
#pragma unroll
        for (int r = 0; r < 4; ++r)
            *reinterpret_cast<v4f*>(
                &AC[((size_t)(isC * 2048 + r0 + rs * 4 + r)) * HH + hq * 4]) =
                acc[r] + bias;
    }
}

// ---------------------------------------------------------------------------
// Kernel 2: fused abs-sum + W2 epilogue (256 blocks x 1024 threads)
// Round-9 attribution: ~36 us, ~28 us of it memory stall. Theory: every XCD
// touched ALL of A+C (4 MB) -> per-XCD L2 thrash -> A served from L3.
// Fix: XCD-aware mapping b=(bid&7)>>1 (assumes round-robin bid->XCD):
// each XCD-pair works on one batch b -> working set A[b]+C[b]+W2 ~ 1 MB,
// L2-resident. Everything else identical to round 8 (verified absmax 0.5).
// ---------------------------------------------------------------------------
__global__ __launch_bounds__(1024) void fused_main(
    const float* __restrict__ A, const float* __restrict__ C,
    const float* __restrict__ W2, const float* __restrict__ b2,
    float* __restrict__ out)
{
    __shared__ __align__(16) v4f scratch[1536];     // 24 KB: qm-partials / red
    __shared__ __align__(16) v4f satp[3][4][16];    // 3 KB
    __shared__ __align__(16) float S[8][HH];        // 8 KB
    const int bid = blockIdx.x;
    const int b   = (bid & 7) >> 1;                          // XCD-pair -> batch
    const int n0  = ((((bid >> 3) << 1) | (bid & 1))) * 8;   // n-tile
    const int t   = threadIdx.x;

    // ---- phase A ----
    const int w    = t >> 6;
    const int l    = t & 63;
    const int hg   = w & 3;
    const int qm   = w >> 2;
    const int hq   = l & 15;
    const int msub = l >> 4;
    const int h0   = hg * 64 + hq * 4;

    const float* Cb = C + ((size_t)(b * NN + n0)) * HH + h0;
    v4f c[8];
#pragma unroll
    for (int j = 0; j < 8; ++j)
        c[j] = *reinterpret_cast<const v4f*>(&Cb[(size_t)j * HH]);

    v4f acc[8], sat = (v4f){0.f, 0.f, 0.f, 0.f};
#pragma unroll
    for (int j = 0; j < 8; ++j) acc[j] = (v4f){0.f, 0.f, 0.f, 0.f};

    // m = qm*128 + i*4 + msub, i = 0..31
    const float* Ab = A + ((size_t)(b * MM + qm * 128 + msub)) * HH + h0;
#pragma unroll 4
    for (int i = 0; i < 32; ++i) {
        const v4f a = *reinterpret_cast<const v4f*>(&Ab[(size_t)i * 4 * HH]);
        sat += a;
#pragma unroll
        for (int j = 0; j < 8; ++j) {
            const v4f s = a + c[j];
            acc[j].x += fabsf(s.x);
            acc[j].y += fabsf(s.y);
            acc[j].z += fabsf(s.z);
            acc[j].w += fabsf(s.w);
        }
    }

    // ---- reduce msub (in-register butterfly over lane bits 4,5) ----
#pragma unroll
    for (int mask = 16; mask <= 32; mask <<= 1) {
#pragma unroll
        for (int j = 0; j < 8; ++j) acc[j] += shfl_xor4(acc[j], mask);
        sat += shfl_xor4(sat, mask);
    }

    // ---- reduce qm via LDS (plain writes, no atomics) ----
    if (qm > 0 && l < 16) {
#pragma unroll
        for (int j = 0; j < 8; ++j)
            scratch[(((qm - 1) * 4 + hg) * 8 + j) * 16 + l] = acc[j];
        satp[qm - 1][hg][l] = sat;
    }
    __syncthreads();

    if (qm == 0 && l < 16) {
#pragma unroll
        for (int p = 0; p < 3; ++p) {
#pragma unroll
            for (int j = 0; j < 8; ++j)
                acc[j] += scratch[((p * 4 + hg) * 8 + j) * 16 + l];
            sat += satp[p][hg][l];
        }
#pragma unroll
        for (int j = 0; j < 8; ++j) {
            const v4f sv = 0.5f * (sat + 512.f * c[j] + acc[j]);
            *reinterpret_cast<v4f*>(&S[j][h0]) = sv;
        }
    }
    __syncthreads();

    // ---- phase C: out = S*W2 + 512*b2, k split 4 ways ----
    const int o0 = (t & 31) * 4;
    const int r  = (t >> 5) & 7;
    const int kq = t >> 8;
    const int k0 = kq * 64;
    v4f a4 = (v4f){0.f, 0.f, 0.f, 0.f};
    const float* w2p = W2 + o0;
#pragma unroll 4
    for (int k = k0; k < k0 + 64; k += 4) {
        const v4f sv = *reinterpret_cast<const v4f*>(&S[r][k]);       // broadcast
        const v4f wA = *reinterpret_cast<const v4f*>(&w2p[(k + 0) * DOUTC]);
        const v4f wB = *reinterpret_cast<const v4f*>(&w2p[(k + 1) * DOUTC]);
        const v4f wC = *reinterpret_cast<const v4f*>(&w2p[(k + 2) * DOUTC]);
        const v4f wD = *reinterpret_cast<const v4f*>(&w2p[(k + 3) * DOUTC]);
        a4 += wA * sv.x;
        a4 += wB * sv.y;
        a4 += wC * sv.z;
        a4 += wD * sv.w;
    }
    if (kq) scratch[(kq - 1) * 256 + (t & 255)] = a4;   // reuse 12 KB of scratch
    __syncthreads();
    if (kq == 0) {
#pragma unroll
        for (int p = 0; p < 3; ++p) a4 += scratch[p * 256 + t];
        a4 += 512.f * (*reinterpret_cast<const v4f*>(&b2[o0]));
        *reinterpret_cast<v4f*>(&out[((size_t)(b * NN + n0 + r)) * DOUTC + o0]) = a4;
    }
}

// ---------------------------------------------------------------------------
extern "C" void kernel_launch(void* const* d_in, const int* in_sizes, int n_in,
                              void* d_out, int out_size, void* d_ws, size_t ws_size,
                              hipStream_t stream) {
    const float* X  = (const float*)d_in[0];
    const float* Y  = (const float*)d_in[1];
    const float* W1 = (const float*)d_in[2];
    const float* b1 = (const float*)d_in[3];
    const float* W2 = (const float*)d_in[4];
    const float* b2 = (const float*)d_in[5];
    float* out = (float*)d_out;

    float* AC = (float*)d_ws;        // 4 MB: A rows 0..2047, C rows 2048..4095
    float* A  = AC;
    float* Cm = AC + 2048 * HH;

    hipLaunchKernelGGL(precompute_ac, dim3(256), dim3(1024), 0, stream,
                       X, Y, W1, b1, AC);
    hipLaunchKernelGGL(fused_main, dim3(256), dim3(1024), 0, stream,
                       A, Cm, W2, b2, out);
}